// Round 5
// baseline (1377.254 us; speedup 1.0000x reference)
//
#include <hip/hip_runtime.h>
#include <hip/hip_bf16.h>
#include <math.h>

#define TT 8192
#define HH 2048
#define DD 2048
#define EE 8
#define NT 32   // K/64 for both GEMMs (K=2048)

typedef short bf16x8 __attribute__((ext_vector_type(8)));
typedef float f32x4 __attribute__((ext_vector_type(4)));

__device__ __forceinline__ ushort f2bf(float f){
  unsigned u = __float_as_uint(f);
  u += 0x7fffu + ((u>>16)&1u);
  return (ushort)(u>>16);
}

#define GLOAD16(SRC,DST) \
  __builtin_amdgcn_global_load_lds((const __attribute__((address_space(1))) void*)(SRC), \
                                   (__attribute__((address_space(3))) void*)(DST), 16, 0, 0)

#define SBAR __builtin_amdgcn_sched_barrier(0)
#define BARR __builtin_amdgcn_s_barrier()
#define WLG  asm volatile("s_waitcnt lgkmcnt(0)" ::: "memory")
#define PRI(x) __builtin_amdgcn_s_setprio(x)

// ---------------- router: fp64 rmsnorm+logits, top-2, expert lists + token map ----------------
__global__ __launch_bounds__(256) void router_kernel(
    const float* __restrict__ x, const float* __restrict__ rscale,
    const float* __restrict__ pes, const float* __restrict__ rw,
    ushort* __restrict__ x16, int* __restrict__ cnt,
    int* __restrict__ tok, float* __restrict__ wgt, int4* __restrict__ tmap)
{
  int t = blockIdx.x;
  int tid = threadIdx.x;
  const float4* xr  = (const float4*)(x + (size_t)t*HH);
  const float4* rs4 = (const float4*)rscale;
  float4 xa = xr[tid], xb = xr[tid+256];
  float4 sa = rs4[tid], sb = rs4[tid+256];
  double xd[8] = {xa.x,xa.y,xa.z,xa.w,xb.x,xb.y,xb.z,xb.w};
  double sd[8] = {sa.x,sa.y,sa.z,sa.w,sb.x,sb.y,sb.z,sb.w};
  double acc[9];
  double ss = 0.0;
  #pragma unroll
  for (int j=0;j<8;j++) ss += xd[j]*xd[j];
  acc[8] = ss;
  double xs[8];
  #pragma unroll
  for (int j=0;j<8;j++) xs[j] = xd[j]*sd[j];
  #pragma unroll
  for (int e=0;e<EE;e++){
    const float4* w4 = (const float4*)(rw + (size_t)e*HH);
    float4 wa = w4[tid], wb = w4[tid+256];
    double wd[8] = {wa.x,wa.y,wa.z,wa.w,wb.x,wb.y,wb.z,wb.w};
    double d = 0.0;
    #pragma unroll
    for (int j=0;j<8;j++) d += xs[j]*wd[j];
    acc[e] = d;
  }
  uint2 pa, pb;
  pa.x = (unsigned)f2bf(xa.x) | ((unsigned)f2bf(xa.y)<<16);
  pa.y = (unsigned)f2bf(xa.z) | ((unsigned)f2bf(xa.w)<<16);
  pb.x = (unsigned)f2bf(xb.x) | ((unsigned)f2bf(xb.y)<<16);
  pb.y = (unsigned)f2bf(xb.z) | ((unsigned)f2bf(xb.w)<<16);
  uint2* xo = (uint2*)(x16 + (size_t)t*HH);
  xo[tid] = pa; xo[tid+256] = pb;

  __shared__ double red[9*256];
  #pragma unroll
  for (int j=0;j<9;j++) red[j*256+tid] = acc[j];
  __syncthreads();
  for (int s=128;s>0;s>>=1){
    if (tid < s){
      #pragma unroll
      for (int j=0;j<9;j++) red[j*256+tid] += red[j*256+tid+s];
    }
    __syncthreads();
  }
  if (tid==0){
    double mean = red[8*256] / (double)HH;
    double rms  = 1.0 / sqrt(mean + 1e-6);
    double sc   = rms / sqrt((double)HH);
    double l[EE];
    #pragma unroll
    for (int e=0;e<EE;e++) l[e] = red[e*256]*sc;
    int i0 = 0;
    #pragma unroll
    for (int e=1;e<EE;e++) if (l[e] > l[i0]) i0 = e;
    int i1 = -1;
    #pragma unroll
    for (int e=0;e<EE;e++){ if (e==i0) continue; if (i1 < 0 || l[e] > l[i1]) i1 = e; }
    double p1 = exp(l[i1]-l[i0]);
    double s  = 1.0 + p1;
    float w0 = (float)((1.0/s) * (double)pes[i0]);
    float w1 = (float)((p1 /s) * (double)pes[i1]);
    int pos0 = atomicAdd(&cnt[i0],1);
    tok[i0*TT+pos0] = t; wgt[i0*TT+pos0] = w0;
    int pos1 = atomicAdd(&cnt[i1],1);
    tok[i1*TT+pos1] = t; wgt[i1*TT+pos1] = w1;
    tmap[t] = make_int4(i0,pos0,i1,pos1);
  }
}

__global__ void scan_kernel(const int* __restrict__ cnt, int* __restrict__ off){
  if (threadIdx.x==0 && blockIdx.x==0){
    int a = 0;
    for (int e=0;e<EE;e++){ off[e]=a; a+=cnt[e]; }
    off[EE]=a;
  }
}

// ---- 8-phase machinery: A via global_load_lds (bf16), B via reg-staged fp32->bf16 ----
// LDS tile: [256 rows][64 cols] bf16 per operand, double buffered. 16B chunk
// swizzle: slot c holds global chunk c ^ (row&7); reads apply same XOR.
#define STA(bb,h,t) do{ \
    GLOAD16(pA[2*(h)  ] + (size_t)(t)*64, &ldsA[bb][(h)*8192        + wid*512]); \
    GLOAD16(pA[2*(h)+1] + (size_t)(t)*64, &ldsA[bb][(h)*8192 + 4096 + wid*512]); }while(0)

// B reg staging: thread owns B-tile row R=tid&255, col-half bch=tid>>8
// (32 fp32 = 8 dwordx4). Written as 4 bf16 chunks with the same XOR swizzle.
// Bank-check: wave = 64 consecutive rows, (chunk^row&7) tiles all 32 banks.
#define BLOAD(t) do{ _Pragma("unroll") \
  for (int j=0;j<8;j++) breg[j] = *(const float4*)(pBsrc + (size_t)(t)*64 + j*4); }while(0)
#define BWRITE(bb) do{ _Pragma("unroll") \
  for (int j=0;j<4;j++){ \
    uint4 v; \
    v.x=(unsigned)f2bf(breg[2*j  ].x)|((unsigned)f2bf(breg[2*j  ].y)<<16); \
    v.y=(unsigned)f2bf(breg[2*j  ].z)|((unsigned)f2bf(breg[2*j  ].w)<<16); \
    v.z=(unsigned)f2bf(breg[2*j+1].x)|((unsigned)f2bf(breg[2*j+1].y)<<16); \
    v.w=(unsigned)f2bf(breg[2*j+1].z)|((unsigned)f2bf(breg[2*j+1].w)<<16); \
    *(uint4*)&ldsB[bb][(bwr<<6) + (((bch*4+j) ^ (bwr&7))<<3)] = v; } }while(0)

#define RD_A(h) do{ _Pragma("unroll") \
  for (int mf=0;mf<4;mf++){ int row=(h)*128 + wm*64 + mf*16 + frow; \
    a[mf][0] = *(const bf16x8*)&As[row*64 + c0]; \
    a[mf][1] = *(const bf16x8*)&As[row*64 + c1]; } }while(0)
#define RD_B(h,bb_) do{ _Pragma("unroll") \
  for (int nf=0;nf<2;nf++){ int row=(h)*128 + wn*32 + nf*16 + frow; \
    bb_[nf][0] = *(const bf16x8*)&Bs[row*64 + c0]; \
    bb_[nf][1] = *(const bf16x8*)&Bs[row*64 + c1]; } }while(0)

#define MMQ(mo,no,bb_) do{ _Pragma("unroll") \
  for (int mf=0;mf<4;mf++){ _Pragma("unroll") \
    for (int nf=0;nf<2;nf++){ \
      acc[(mo)+mf][(no)+nf] = __builtin_amdgcn_mfma_f32_16x16x32_bf16(a[mf][0], bb_[nf][0], acc[(mo)+mf][(no)+nf],0,0,0); \
      acc[(mo)+mf][(no)+nf] = __builtin_amdgcn_mfma_f32_16x16x32_bf16(a[mf][1], bb_[nf][1], acc[(mo)+mf][(no)+nf],0,0,0); } } }while(0)

// K-loop (round-2/4 MMQ/RD core, measured best). Staging slots:
//  P2: STA A(t+2) half0 (h0 of cur last read at P1)
//  P3: BWRITE B(t+1) -> ldsB[nxt] (fully read during tile t-1); compiler's
//      exact vmcnt on breg also drains A(t+1) gloads before tile t+1.
//  P4: STA A(t+2) half1 (h1 read at P3) + BLOAD B(t+2) regs (consumed P3(t+1))
#define KLOOP for (int t=0;t<NT;t++){ \
    int cur=t&1, nxt=cur^1; \
    const ushort* As=&ldsA[cur][0]; const ushort* Bs=&ldsB[cur][0]; \
    RD_A(0); RD_B(0,b0); \
    SBAR; BARR; WLG; SBAR; PRI(1); MMQ(0,0,b0); PRI(0); SBAR; BARR; SBAR; \
    RD_B(1,b1); \
    if (t+2<NT) STA(cur,0,t+2); \
    SBAR; BARR; WLG; SBAR; PRI(1); MMQ(0,2,b1); PRI(0); SBAR; BARR; SBAR; \
    RD_A(1); \
    if (t+1<NT) BWRITE(nxt); \
    SBAR; BARR; WLG; SBAR; PRI(1); MMQ(4,0,b0); PRI(0); SBAR; BARR; SBAR; \
    if (t+2<NT){ STA(cur,1,t+2); BLOAD(t+2); } \
    SBAR; BARR; SBAR; PRI(1); MMQ(4,2,b1); PRI(0); SBAR; BARR; SBAR; \
  }

// Prologue: B(0) regs -> A(0),A(1) gloads -> write B(0) (compiler vmcnt(8))
// -> B(1) regs -> manual vmcnt(12) drains A(0) -> lgkm -> barrier.
#define PROLOGUE \
  BLOAD(0); \
  STA(0,0,0); STA(0,1,0); STA(1,0,1); STA(1,1,1); \
  BWRITE(0); \
  BLOAD(1); \
  asm volatile("s_waitcnt vmcnt(12)" ::: "memory"); \
  WLG; BARR; SBAR;

// ---------------- GEMM1: 256 rows x 128 h-cols, gate/up interleaved in B ----------------
__global__ __launch_bounds__(512,2) void ffn1_kernel(
    const ushort* __restrict__ x16, const float* __restrict__ w13,
    const int* __restrict__ cnt, const int* __restrict__ off,
    const int* __restrict__ tok, ushort* __restrict__ hbuf)
{
  // XCD-bijective swizzle (nwg=4096): XCD x owns expert x; n0 fastest within.
  int f = blockIdx.x + 16*(blockIdx.y + 32*blockIdx.z);
  int w = ((f&7)<<9) + (f>>3);
  int e  = w >> 9;
  int n0 = (w & 15) << 7;
  int m0 = ((w >> 4) & 31) << 8;
  int ce = cnt[e];
  if (m0 >= ce) return;

  __shared__ ushort ldsA[2][256*64];
  __shared__ ushort ldsB[2][256*64];

  int tid = threadIdx.x, wid = tid>>6, lane = tid&63;
  int wm = wid>>2, wn = wid&3;
  int frow = lane&15, klane = lane>>4;
  int c0 = ((klane  ) ^ (frow&7))<<3;
  int c1 = ((klane+4) ^ (frow&7))<<3;

  int r   = wid*8 + (lane>>3);             // A staging row base (0..63)
  int csw = ((lane&7) ^ (lane>>3))<<3;     // inverse-swizzled A source chunk

  const ushort* pA[4];
  int oe = off[e];
  #pragma unroll
  for (int k=0;k<4;k++){
    int R  = k*64 + r;
    int ar = min(m0+R, ce-1);
    pA[k] = x16 + (size_t)tok[e*TT+ar]*HH + csw;
  }
  // B reg-staging source: tile row R -> w13 row (interleaved gate/up mapping)
  int bwr = tid & 255, bch = tid >> 8;
  const float* pBsrc = w13 + (size_t)e*(2*DD)*HH
                     + (size_t)(((bwr>>4)&1)*DD + n0 + (bwr>>5)*16 + (bwr&15))*HH
                     + bch*32;

  f32x4 acc[8][4];
  #pragma unroll
  for (int i=0;i<8;i++)
    #pragma unroll
    for (int j=0;j<4;j++) acc[i][j] = {0.f,0.f,0.f,0.f};
  bf16x8 a[4][2], b0[2][2], b1[2][2];
  float4 breg[8];

  PROLOGUE
  KLOOP

  #pragma unroll
  for (int mf=0;mf<8;mf++){
    int rb = ((mf<4)? wm*64 + mf*16 : 128 + wm*64 + (mf-4)*16) + klane*4;
    #pragma unroll
    for (int q=0;q<4;q++){
      int gm = m0 + rb + q;
      if (gm < ce){
        size_t hrow = (size_t)(oe+gm)*DD;
        #pragma unroll
        for (int pp=0;pp<2;pp++){
          float g = acc[mf][2*pp][q], u = acc[mf][2*pp+1][q];
          float t2 = 1.5957691216057308f*(g + 0.044715f*g*g*g);
          float sg = 1.f/(1.f+__expf(-t2));        // 0.5*(1+tanh(t)) = sigmoid(2t)
          hbuf[hrow + n0 + pp*64 + wn*16 + frow] = f2bf(g*u*sg);
        }
      }
    }
  }
}

// ---------------- GEMM2: 256 rows x 256 out-cols -> slot-major y (bf16, no atomics) ----------------
__global__ __launch_bounds__(512,2) void ffn2_kernel(
    const ushort* __restrict__ hbuf, const float* __restrict__ w2,
    const int* __restrict__ cnt, const int* __restrict__ off,
    ushort* __restrict__ ybuf)
{
  // XCD-bijective swizzle (nwg=2048): XCD x owns expert x; n0 fastest.
  int f = blockIdx.x + 8*(blockIdx.y + 32*blockIdx.z);
  int w = ((f&7)<<8) + (f>>3);
  int e  = w >> 8;
  int n0 = (w & 7) << 8;
  int m0 = ((w >> 3) & 31) << 8;
  int ce = cnt[e];
  if (m0 >= ce) return;

  __shared__ ushort ldsA[2][256*64];
  __shared__ ushort ldsB[2][256*64];

  int tid = threadIdx.x, wid = tid>>6, lane = tid&63;
  int wm = wid>>2, wn = wid&3;
  int frow = lane&15, klane = lane>>4;
  int c0 = ((klane  ) ^ (frow&7))<<3;
  int c1 = ((klane+4) ^ (frow&7))<<3;

  int r   = wid*8 + (lane>>3);
  int csw = ((lane&7) ^ (lane>>3))<<3;

  const ushort* pA[4];
  int oe = off[e];
  #pragma unroll
  for (int k=0;k<4;k++){
    int R  = k*64 + r;
    int ar = oe + min(m0+R, ce-1);
    pA[k] = hbuf + (size_t)ar*DD + csw;
  }
  int bwr = tid & 255, bch = tid >> 8;
  const float* pBsrc = w2 + (size_t)e*HH*DD + (size_t)(n0 + bwr)*DD + bch*32;

  f32x4 acc[8][4];
  #pragma unroll
  for (int i=0;i<8;i++)
    #pragma unroll
    for (int j=0;j<4;j++) acc[i][j] = {0.f,0.f,0.f,0.f};
  bf16x8 a[4][2], b0[2][2], b1[2][2];
  float4 breg[8];

  PROLOGUE
  KLOOP

  #pragma unroll
  for (int mf=0;mf<8;mf++){
    int rb = ((mf<4)? wm*64 + mf*16 : 128 + wm*64 + (mf-4)*16) + klane*4;
    #pragma unroll
    for (int q=0;q<4;q++){
      int gm = m0 + rb + q;
      if (gm < ce){
        size_t yrow = (size_t)(oe+gm)*HH;
        #pragma unroll
        for (int nf=0;nf<4;nf++){
          int col = (nf>>1)*128 + wn*32 + (nf&1)*16 + frow;
          ybuf[yrow + n0 + col] = f2bf(acc[mf][nf][q]);   // plain store, no RMW
        }
      }
    }
  }
}

// ---------------- combine: out[t] = w0*y[slot0] + w1*y[slot1] (coalesced gather) ----------------
__global__ __launch_bounds__(256) void combine_kernel(
    const ushort* __restrict__ ybuf, const int4* __restrict__ tmap,
    const float* __restrict__ wgt, const int* __restrict__ off,
    float* __restrict__ out)
{
  int t = blockIdx.x, tid = threadIdx.x;
  int4 m = tmap[t];
  float w0 = wgt[m.x*TT + m.y];
  float w1 = wgt[m.z*TT + m.w];
  const ushort* y0 = ybuf + (size_t)(off[m.x] + m.y)*HH + tid*8;
  const ushort* y1 = ybuf + (size_t)(off[m.z] + m.w)*HH + tid*8;
  uint4 v0 = *(const uint4*)y0;
  uint4 v1 = *(const uint4*)y1;
  float* o = out + (size_t)t*HH + tid*8;
  const unsigned* a0 = (const unsigned*)&v0;
  const unsigned* a1 = (const unsigned*)&v1;
  float r[8];
  #pragma unroll
  for (int j=0;j<4;j++){
    float lo0 = __uint_as_float(a0[j]<<16), hi0 = __uint_as_float(a0[j]&0xffff0000u);
    float lo1 = __uint_as_float(a1[j]<<16), hi1 = __uint_as_float(a1[j]&0xffff0000u);
    r[2*j]   = w0*lo0 + w1*lo1;
    r[2*j+1] = w0*hi0 + w1*hi1;
  }
  *(float4*)o     = make_float4(r[0],r[1],r[2],r[3]);
  *(float4*)(o+4) = make_float4(r[4],r[5],r[6],r[7]);
}

extern "C" void kernel_launch(void* const* d_in, const int* in_sizes, int n_in,
                              void* d_out, int out_size, void* d_ws, size_t ws_size,
                              hipStream_t stream)
{
  const float* x    = (const float*)d_in[0];
  const float* rsc  = (const float*)d_in[1];
  const float* pes  = (const float*)d_in[2];
  const float* rw   = (const float*)d_in[3];
  const float* w13f = (const float*)d_in[4];
  const float* w2f  = (const float*)d_in[5];
  float* out = (float*)d_out;

  char* ws = (char*)d_ws;
  size_t o_x16 = 0;
  size_t o_h   = o_x16 + (size_t)TT*HH*2;          // x16:  32 MiB
  size_t o_y   = o_h   + (size_t)2*TT*DD*2;        // h:    64 MiB
  size_t o_cnt = o_y   + (size_t)2*TT*HH*2;        // y:    64 MiB
  size_t o_off = o_cnt + 128;
  size_t o_tok = o_off + 128;
  size_t o_wgt = o_tok + (size_t)EE*TT*4;
  size_t o_map = o_wgt + (size_t)EE*TT*4;
  size_t need  = o_map + (size_t)TT*16;            // ~162 MB

  if (ws_size < need){ hipMemsetAsync(d_out, 0, (size_t)TT*HH*4, stream); return; }

  ushort* x16 = (ushort*)(ws + o_x16);
  ushort* hbuf= (ushort*)(ws + o_h);
  ushort* ybuf= (ushort*)(ws + o_y);
  int*   cnt  = (int*)(ws + o_cnt);
  int*   off  = (int*)(ws + o_off);
  int*   tok  = (int*)(ws + o_tok);
  float* wgt  = (float*)(ws + o_wgt);
  int4*  tmap = (int4*)(ws + o_map);

  hipMemsetAsync(cnt, 0, EE*sizeof(int), stream);
  router_kernel<<<TT,256,0,stream>>>(x, rsc, pes, rw, x16, cnt, tok, wgt, tmap);
  scan_kernel<<<1,64,0,stream>>>(cnt, off);
  dim3 g1(DD/128, TT/256, EE);   // 16 x 32 x 8 = 4096
  ffn1_kernel<<<g1,512,0,stream>>>(x16, w13f, cnt, off, tok, hbuf);
  dim3 g2(HH/256, TT/256, EE);   // 8 x 32 x 8 = 2048
  ffn2_kernel<<<g2,512,0,stream>>>(hbuf, w2f, cnt, off, ybuf);
  combine_kernel<<<TT,256,0,stream>>>(ybuf, tmap, wgt, off, out);
}

// Round 6
// 711.814 us; speedup vs baseline: 1.9349x; 1.9349x over previous
//
#include <hip/hip_runtime.h>
#include <hip/hip_bf16.h>
#include <math.h>

#define TT 8192
#define HH 2048
#define DD 2048
#define EE 8
#define NT 32   // K/64 for both GEMMs (K=2048)

typedef short bf16x8 __attribute__((ext_vector_type(8)));
typedef float f32x4 __attribute__((ext_vector_type(4)));

__device__ __forceinline__ ushort f2bf(float f){
  unsigned u = __float_as_uint(f);
  u += 0x7fffu + ((u>>16)&1u);
  return (ushort)(u>>16);
}

#define GLOAD16(SRC,DST) \
  __builtin_amdgcn_global_load_lds((const __attribute__((address_space(1))) void*)(SRC), \
                                   (__attribute__((address_space(3))) void*)(DST), 16, 0, 0)

#define SBAR __builtin_amdgcn_sched_barrier(0)
#define BARR __builtin_amdgcn_s_barrier()
#define WLG  asm volatile("s_waitcnt lgkmcnt(0)" ::: "memory")
#define WVM6 asm volatile("s_waitcnt vmcnt(6)" ::: "memory")
#define PRI(x) __builtin_amdgcn_s_setprio(x)

// 8-elem fp32 -> packed bf16 convert step (used by the fused cvt tails)
#define CVT8(SRCP,DSTP,CI) do{ \
    const float* _s = (SRCP) + (CI)*8; \
    float4 _a = *(const float4*)_s, _b = *(const float4*)(_s+4); \
    uint4 _v; \
    _v.x=(unsigned)f2bf(_a.x)|((unsigned)f2bf(_a.y)<<16); \
    _v.y=(unsigned)f2bf(_a.z)|((unsigned)f2bf(_a.w)<<16); \
    _v.z=(unsigned)f2bf(_b.x)|((unsigned)f2bf(_b.y)<<16); \
    _v.w=(unsigned)f2bf(_b.z)|((unsigned)f2bf(_b.w)<<16); \
    *(uint4*)((DSTP) + (CI)*8) = _v; }while(0)

// ---------------- router: fp64 rmsnorm+logits, top-2, expert lists + token map
// ---------------- + fused w13 fp32->bf16 conversion tail ----------------
__global__ __launch_bounds__(256) void router_kernel(
    const float* __restrict__ x, const float* __restrict__ rscale,
    const float* __restrict__ pes, const float* __restrict__ rw,
    ushort* __restrict__ x16, int* __restrict__ cnt,
    int* __restrict__ tok, float* __restrict__ wgt, int4* __restrict__ tmap,
    const float* __restrict__ w13f, ushort* __restrict__ w13b)
{
  int t = blockIdx.x;
  int tid = threadIdx.x;
  const float4* xr  = (const float4*)(x + (size_t)t*HH);
  const float4* rs4 = (const float4*)rscale;
  float4 xa = xr[tid], xb = xr[tid+256];
  float4 sa = rs4[tid], sb = rs4[tid+256];
  double xd[8] = {xa.x,xa.y,xa.z,xa.w,xb.x,xb.y,xb.z,xb.w};
  double sd[8] = {sa.x,sa.y,sa.z,sa.w,sb.x,sb.y,sb.z,sb.w};
  double acc[9];
  double ss = 0.0;
  #pragma unroll
  for (int j=0;j<8;j++) ss += xd[j]*xd[j];
  acc[8] = ss;
  double xs[8];
  #pragma unroll
  for (int j=0;j<8;j++) xs[j] = xd[j]*sd[j];
  #pragma unroll
  for (int e=0;e<EE;e++){
    const float4* w4 = (const float4*)(rw + (size_t)e*HH);
    float4 wa = w4[tid], wb = w4[tid+256];
    double wd[8] = {wa.x,wa.y,wa.z,wa.w,wb.x,wb.y,wb.z,wb.w};
    double d = 0.0;
    #pragma unroll
    for (int j=0;j<8;j++) d += xs[j]*wd[j];
    acc[e] = d;
  }
  uint2 pa, pb;
  pa.x = (unsigned)f2bf(xa.x) | ((unsigned)f2bf(xa.y)<<16);
  pa.y = (unsigned)f2bf(xa.z) | ((unsigned)f2bf(xa.w)<<16);
  pb.x = (unsigned)f2bf(xb.x) | ((unsigned)f2bf(xb.y)<<16);
  pb.y = (unsigned)f2bf(xb.z) | ((unsigned)f2bf(xb.w)<<16);
  uint2* xo = (uint2*)(x16 + (size_t)t*HH);
  xo[tid] = pa; xo[tid+256] = pb;

  __shared__ double red[9*256];
  #pragma unroll
  for (int j=0;j<9;j++) red[j*256+tid] = acc[j];
  __syncthreads();
  for (int s=128;s>0;s>>=1){
    if (tid < s){
      #pragma unroll
      for (int j=0;j<9;j++) red[j*256+tid] += red[j*256+tid+s];
    }
    __syncthreads();
  }
  if (tid==0){
    double mean = red[8*256] / (double)HH;
    double rms  = 1.0 / sqrt(mean + 1e-6);
    double sc   = rms / sqrt((double)HH);
    double l[EE];
    #pragma unroll
    for (int e=0;e<EE;e++) l[e] = red[e*256]*sc;
    int i0 = 0;
    #pragma unroll
    for (int e=1;e<EE;e++) if (l[e] > l[i0]) i0 = e;
    int i1 = -1;
    #pragma unroll
    for (int e=0;e<EE;e++){ if (e==i0) continue; if (i1 < 0 || l[e] > l[i1]) i1 = e; }
    double p1 = exp(l[i1]-l[i0]);
    double s  = 1.0 + p1;
    float w0 = (float)((1.0/s) * (double)pes[i0]);
    float w1 = (float)((p1 /s) * (double)pes[i1]);
    int pos0 = atomicAdd(&cnt[i0],1);
    tok[i0*TT+pos0] = t; wgt[i0*TT+pos0] = w0;
    int pos1 = atomicAdd(&cnt[i1],1);
    tok[i1*TT+pos1] = t; wgt[i1*TT+pos1] = w1;
    tmap[t] = make_int4(i0,pos0,i1,pos1);
  }

  // ---- fused tail: convert w13 fp32 -> bf16 (4 grid-strided vec8 chunks) ----
  {
    size_t gid    = (size_t)t*256 + tid;
    size_t nchunk = (size_t)EE*2*DD*HH/8;   // 8,388,608
    size_t stride = (size_t)TT*256;         // 2,097,152
    for (size_t c = gid; c < nchunk; c += stride) CVT8(w13f, w13b, c);
  }
}

__global__ void scan_kernel(const int* __restrict__ cnt, int* __restrict__ off){
  if (threadIdx.x==0 && blockIdx.x==0){
    int a = 0;
    for (int e=0;e<EE;e++){ off[e]=a; a+=cnt[e]; }
    off[EE]=a;
  }
}

// ---- 8-phase machinery (round-2/4 schedule: reads before barrier, MFMA after) ----
// LDS tile: [256 rows][64 cols] bf16 per operand, double buffered. 16B chunk
// swizzle: slot c holds global chunk c ^ (row&7); reads apply same XOR.
#define STA(bb,h,t) do{ \
    GLOAD16(pA[2*(h)  ] + (size_t)(t)*64, &ldsA[bb][(h)*8192        + wid*512]); \
    GLOAD16(pA[2*(h)+1] + (size_t)(t)*64, &ldsA[bb][(h)*8192 + 4096 + wid*512]); }while(0)
#define STB(bb,h,t) do{ \
    GLOAD16(pB[2*(h)  ] + (size_t)(t)*64, &ldsB[bb][(h)*8192        + wid*512]); \
    GLOAD16(pB[2*(h)+1] + (size_t)(t)*64, &ldsB[bb][(h)*8192 + 4096 + wid*512]); }while(0)

#define RD_A(h) do{ _Pragma("unroll") \
  for (int mf=0;mf<4;mf++){ int row=(h)*128 + wm*64 + mf*16 + frow; \
    a[mf][0] = *(const bf16x8*)&As[row*64 + c0]; \
    a[mf][1] = *(const bf16x8*)&As[row*64 + c1]; } }while(0)
#define RD_B(h,bb_) do{ _Pragma("unroll") \
  for (int nf=0;nf<2;nf++){ int row=(h)*128 + wn*32 + nf*16 + frow; \
    bb_[nf][0] = *(const bf16x8*)&Bs[row*64 + c0]; \
    bb_[nf][1] = *(const bf16x8*)&Bs[row*64 + c1]; } }while(0)

#define MMQ(mo,no,bb_) do{ _Pragma("unroll") \
  for (int mf=0;mf<4;mf++){ _Pragma("unroll") \
    for (int nf=0;nf<2;nf++){ \
      acc[(mo)+mf][(no)+nf] = __builtin_amdgcn_mfma_f32_16x16x32_bf16(a[mf][0], bb_[nf][0], acc[(mo)+mf][(no)+nf],0,0,0); \
      acc[(mo)+mf][(no)+nf] = __builtin_amdgcn_mfma_f32_16x16x32_bf16(a[mf][1], bb_[nf][1], acc[(mo)+mf][(no)+nf],0,0,0); } } }while(0)

// Round-2/4 K-loop (measured best): 4 phases/K-tile; stages into t+1/t+2 slots;
// vmcnt(6) once per K-tile, never 0 mid-loop.
#define KLOOP for (int t=0;t<NT;t++){ \
    int cur=t&1, nxt=cur^1; \
    const ushort* As=&ldsA[cur][0]; const ushort* Bs=&ldsB[cur][0]; \
    RD_A(0); RD_B(0,b0); \
    if (t+1<NT) STA(nxt,1,t+1); \
    SBAR; BARR; WLG; SBAR; PRI(1); MMQ(0,0,b0); PRI(0); SBAR; BARR; SBAR; \
    RD_B(1,b1); \
    if (t+2<NT) STA(cur,0,t+2); \
    SBAR; BARR; WLG; SBAR; PRI(1); MMQ(0,2,b1); PRI(0); SBAR; BARR; SBAR; \
    RD_A(1); \
    if (t+2<NT) STB(cur,0,t+2); \
    SBAR; BARR; WLG; SBAR; PRI(1); MMQ(4,0,b0); PRI(0); SBAR; BARR; SBAR; \
    if (t+2<NT) STB(cur,1,t+2); \
    SBAR; BARR; SBAR; PRI(1); MMQ(4,2,b1); PRI(0); SBAR; WVM6; BARR; SBAR; \
  }

#define PROLOGUE \
  STA(0,0,0); STB(0,0,0); STB(0,1,0); STA(0,1,0); \
  STA(1,0,1); STB(1,0,1); STB(1,1,1); \
  SBAR; WVM6; BARR; SBAR;

// ---------------- GEMM1: 256 rows x 128 h-cols, gate/up interleaved in B ----------------
// + fused w2 fp32->bf16 conversion tail (runs on ALL blocks incl. early-exit)
__global__ __launch_bounds__(512,2) void ffn1_kernel(
    const ushort* __restrict__ x16, const ushort* __restrict__ w13,
    const int* __restrict__ cnt, const int* __restrict__ off,
    const int* __restrict__ tok, ushort* __restrict__ hbuf,
    const float* __restrict__ w2f, ushort* __restrict__ w2b)
{
  // XCD-bijective swizzle (nwg=4096): XCD x owns expert x; n0 fastest within.
  int f = blockIdx.x + 16*(blockIdx.y + 32*blockIdx.z);
  int w = ((f&7)<<9) + (f>>3);
  int e  = w >> 9;
  int n0 = (w & 15) << 7;
  int m0 = ((w >> 4) & 31) << 8;
  int ce = cnt[e];

  __shared__ ushort ldsA[2][256*64];
  __shared__ ushort ldsB[2][256*64];

  int tid = threadIdx.x, wid = tid>>6, lane = tid&63;

  if (m0 < ce){
    int wm = wid>>2, wn = wid&3;
    int frow = lane&15, klane = lane>>4;
    int c0 = ((klane  ) ^ (frow&7))<<3;
    int c1 = ((klane+4) ^ (frow&7))<<3;

    int r   = wid*8 + (lane>>3);             // staging row base (0..63)
    int csw = ((lane&7) ^ (lane>>3))<<3;     // inverse-swizzled source chunk

    const ushort* pA[4]; const ushort* pB[4];
    int oe = off[e];
    #pragma unroll
    for (int k=0;k<4;k++){
      int R  = k*64 + r;
      int ar = min(m0+R, ce-1);
      pA[k] = x16 + (size_t)tok[e*TT+ar]*HH + csw;
      int p = 2*k + (r>>5), mat = (r>>4)&1;
      pB[k] = w13 + (size_t)e*(2*DD)*HH + (size_t)(mat*DD + n0 + p*16 + (r&15))*HH + csw;
    }

    f32x4 acc[8][4];
    #pragma unroll
    for (int i=0;i<8;i++)
      #pragma unroll
      for (int j=0;j<4;j++) acc[i][j] = {0.f,0.f,0.f,0.f};
    bf16x8 a[4][2], b0[2][2], b1[2][2];

    PROLOGUE
    KLOOP

    #pragma unroll
    for (int mf=0;mf<8;mf++){
      int rb = ((mf<4)? wm*64 + mf*16 : 128 + wm*64 + (mf-4)*16) + klane*4;
      #pragma unroll
      for (int q=0;q<4;q++){
        int gm = m0 + rb + q;
        if (gm < ce){
          size_t hrow = (size_t)(oe+gm)*DD;
          #pragma unroll
          for (int pp=0;pp<2;pp++){
            float g = acc[mf][2*pp][q], u = acc[mf][2*pp+1][q];
            float t2 = 1.5957691216057308f*(g + 0.044715f*g*g*g);
            float sg = 1.f/(1.f+__expf(-t2));        // 0.5*(1+tanh(t)) = sigmoid(2t)
            hbuf[hrow + n0 + pp*64 + wn*16 + frow] = f2bf(g*u*sg);
          }
        }
      }
    }
  }

  // ---- fused tail: convert w2 fp32 -> bf16 (2 grid-strided vec8 chunks) ----
  {
    size_t gid    = (size_t)f*512 + tid;
    size_t nchunk = (size_t)EE*HH*DD/8;      // 4,194,304
    size_t stride = (size_t)4096*512;        // 2,097,152
    for (size_t c = gid; c < nchunk; c += stride) CVT8(w2f, w2b, c);
  }
}

// ---------------- GEMM2: 256 rows x 256 out-cols -> slot-major y (bf16, no atomics) ----------------
__global__ __launch_bounds__(512,2) void ffn2_kernel(
    const ushort* __restrict__ hbuf, const ushort* __restrict__ w2,
    const int* __restrict__ cnt, const int* __restrict__ off,
    ushort* __restrict__ ybuf)
{
  // XCD-bijective swizzle (nwg=2048): XCD x owns expert x; n0 fastest.
  int f = blockIdx.x + 8*(blockIdx.y + 32*blockIdx.z);
  int w = ((f&7)<<8) + (f>>3);
  int e  = w >> 8;
  int n0 = (w & 7) << 8;
  int m0 = ((w >> 3) & 31) << 8;
  int ce = cnt[e];
  if (m0 >= ce) return;

  __shared__ ushort ldsA[2][256*64];
  __shared__ ushort ldsB[2][256*64];

  int tid = threadIdx.x, wid = tid>>6, lane = tid&63;
  int wm = wid>>2, wn = wid&3;
  int frow = lane&15, klane = lane>>4;
  int c0 = ((klane  ) ^ (frow&7))<<3;
  int c1 = ((klane+4) ^ (frow&7))<<3;

  int r   = wid*8 + (lane>>3);
  int csw = ((lane&7) ^ (lane>>3))<<3;

  const ushort* pA[4]; const ushort* pB[4];
  int oe = off[e];
  #pragma unroll
  for (int k=0;k<4;k++){
    int R  = k*64 + r;
    int ar = oe + min(m0+R, ce-1);
    pA[k] = hbuf + (size_t)ar*DD + csw;
    pB[k] = w2 + (size_t)e*HH*DD + (size_t)(n0 + R)*DD + csw;
  }

  f32x4 acc[8][4];
  #pragma unroll
  for (int i=0;i<8;i++)
    #pragma unroll
    for (int j=0;j<4;j++) acc[i][j] = {0.f,0.f,0.f,0.f};
  bf16x8 a[4][2], b0[2][2], b1[2][2];

  PROLOGUE
  KLOOP

  #pragma unroll
  for (int mf=0;mf<8;mf++){
    int rb = ((mf<4)? wm*64 + mf*16 : 128 + wm*64 + (mf-4)*16) + klane*4;
    #pragma unroll
    for (int q=0;q<4;q++){
      int gm = m0 + rb + q;
      if (gm < ce){
        size_t yrow = (size_t)(oe+gm)*HH;
        #pragma unroll
        for (int nf=0;nf<4;nf++){
          int col = (nf>>1)*128 + wn*32 + (nf&1)*16 + frow;
          ybuf[yrow + n0 + col] = f2bf(acc[mf][nf][q]);   // plain store, no RMW
        }
      }
    }
  }
}

// ---------------- combine: out[t] = w0*y[slot0] + w1*y[slot1] (coalesced gather) ----------------
__global__ __launch_bounds__(256) void combine_kernel(
    const ushort* __restrict__ ybuf, const int4* __restrict__ tmap,
    const float* __restrict__ wgt, const int* __restrict__ off,
    float* __restrict__ out)
{
  int t = blockIdx.x, tid = threadIdx.x;
  int4 m = tmap[t];
  float w0 = wgt[m.x*TT + m.y];
  float w1 = wgt[m.z*TT + m.w];
  const ushort* y0 = ybuf + (size_t)(off[m.x] + m.y)*HH + tid*8;
  const ushort* y1 = ybuf + (size_t)(off[m.z] + m.w)*HH + tid*8;
  uint4 v0 = *(const uint4*)y0;
  uint4 v1 = *(const uint4*)y1;
  float* o = out + (size_t)t*HH + tid*8;
  const unsigned* a0 = (const unsigned*)&v0;
  const unsigned* a1 = (const unsigned*)&v1;
  float r[8];
  #pragma unroll
  for (int j=0;j<4;j++){
    float lo0 = __uint_as_float(a0[j]<<16), hi0 = __uint_as_float(a0[j]&0xffff0000u);
    float lo1 = __uint_as_float(a1[j]<<16), hi1 = __uint_as_float(a1[j]&0xffff0000u);
    r[2*j]   = w0*lo0 + w1*lo1;
    r[2*j+1] = w0*hi0 + w1*hi1;
  }
  *(float4*)o     = make_float4(r[0],r[1],r[2],r[3]);
  *(float4*)(o+4) = make_float4(r[4],r[5],r[6],r[7]);
}

extern "C" void kernel_launch(void* const* d_in, const int* in_sizes, int n_in,
                              void* d_out, int out_size, void* d_ws, size_t ws_size,
                              hipStream_t stream)
{
  const float* x    = (const float*)d_in[0];
  const float* rsc  = (const float*)d_in[1];
  const float* pes  = (const float*)d_in[2];
  const float* rw   = (const float*)d_in[3];
  const float* w13f = (const float*)d_in[4];
  const float* w2f  = (const float*)d_in[5];
  float* out = (float*)d_out;

  char* ws = (char*)d_ws;
  size_t o_x16 = 0;
  size_t o_w13 = o_x16 + (size_t)TT*HH*2;          // x16:  32 MiB
  size_t o_w2  = o_w13 + (size_t)EE*2*DD*HH*2;     // w13b: 128 MiB (ybuf aliases after ffn1)
  size_t o_h   = o_w2  + (size_t)EE*HH*DD*2;       // w2b:  64 MiB
  size_t o_cnt = o_h   + (size_t)2*TT*DD*2;        // h:    64 MiB
  size_t o_off = o_cnt + 128;
  size_t o_tok = o_off + 128;
  size_t o_wgt = o_tok + (size_t)EE*TT*4;
  size_t o_map = o_wgt + (size_t)EE*TT*4;
  size_t need  = o_map + (size_t)TT*16;

  if (ws_size < need){ hipMemsetAsync(d_out, 0, (size_t)TT*HH*4, stream); return; }

  ushort* x16 = (ushort*)(ws + o_x16);
  ushort* w13b= (ushort*)(ws + o_w13);
  ushort* w2b = (ushort*)(ws + o_w2);
  ushort* hbuf= (ushort*)(ws + o_h);
  ushort* ybuf= (ushort*)(ws + o_w13);             // alias: w13b dead after ffn1
  int*   cnt  = (int*)(ws + o_cnt);
  int*   off  = (int*)(ws + o_off);
  int*   tok  = (int*)(ws + o_tok);
  float* wgt  = (float*)(ws + o_wgt);
  int4*  tmap = (int4*)(ws + o_map);

  hipMemsetAsync(cnt, 0, EE*sizeof(int), stream);
  router_kernel<<<TT,256,0,stream>>>(x, rsc, pes, rw, x16, cnt, tok, wgt, tmap, w13f, w13b);
  scan_kernel<<<1,64,0,stream>>>(cnt, off);
  dim3 g1(DD/128, TT/256, EE);   // 16 x 32 x 8 = 4096
  ffn1_kernel<<<g1,512,0,stream>>>(x16, w13b, cnt, off, tok, hbuf, w2f, w2b);
  dim3 g2(HH/256, TT/256, EE);   // 8 x 32 x 8 = 2048
  ffn2_kernel<<<g2,512,0,stream>>>(hbuf, w2b, cnt, off, ybuf);
  combine_kernel<<<TT,256,0,stream>>>(ybuf, tmap, wgt, off, out);
}

// Round 7
// 691.729 us; speedup vs baseline: 1.9910x; 1.0290x over previous
//
#include <hip/hip_runtime.h>
#include <hip/hip_bf16.h>
#include <math.h>

#define TT 8192
#define HH 2048
#define DD 2048
#define EE 8
#define NT 32   // K/64 for both GEMMs (K=2048)

typedef short bf16x8 __attribute__((ext_vector_type(8)));
typedef float f32x4 __attribute__((ext_vector_type(4)));
typedef float f32x4v __attribute__((ext_vector_type(4)));
typedef unsigned u32x4 __attribute__((ext_vector_type(4)));

__device__ __forceinline__ ushort f2bf(float f){
  unsigned u = __float_as_uint(f);
  u += 0x7fffu + ((u>>16)&1u);
  return (ushort)(u>>16);
}

#define GLOAD16(SRC,DST) \
  __builtin_amdgcn_global_load_lds((const __attribute__((address_space(1))) void*)(SRC), \
                                   (__attribute__((address_space(3))) void*)(DST), 16, 0, 0)

#define SBAR __builtin_amdgcn_sched_barrier(0)
#define BARR __builtin_amdgcn_s_barrier()
#define WLG  asm volatile("s_waitcnt lgkmcnt(0)" ::: "memory")
#define WVM6 asm volatile("s_waitcnt vmcnt(6)" ::: "memory")
#define PRI(x) __builtin_amdgcn_s_setprio(x)

// 8-elem fp32 -> packed bf16 convert step. fp32 source reads are NON-TEMPORAL
// (never re-read; keeps L2/L3 free for the bf16 panels the GEMMs reuse).
// bf16 dest stores stay temporal (L3 serves the GEMM re-reads).
#define CVT8(SRCP,DSTP,CI) do{ \
    const f32x4v* _p = (const f32x4v*)((SRCP) + (CI)*8); \
    f32x4v _a = __builtin_nontemporal_load(_p); \
    f32x4v _b = __builtin_nontemporal_load(_p+1); \
    u32x4 _v; \
    _v.x=(unsigned)f2bf(_a.x)|((unsigned)f2bf(_a.y)<<16); \
    _v.y=(unsigned)f2bf(_a.z)|((unsigned)f2bf(_a.w)<<16); \
    _v.z=(unsigned)f2bf(_b.x)|((unsigned)f2bf(_b.y)<<16); \
    _v.w=(unsigned)f2bf(_b.z)|((unsigned)f2bf(_b.w)<<16); \
    *(u32x4*)((DSTP) + (CI)*8) = _v; }while(0)

// ---------------- router: fp64 rmsnorm+logits, top-2, expert lists + token map
// ---------------- + fused w13 fp32->bf16 conversion tail ----------------
__global__ __launch_bounds__(256) void router_kernel(
    const float* __restrict__ x, const float* __restrict__ rscale,
    const float* __restrict__ pes, const float* __restrict__ rw,
    ushort* __restrict__ x16, int* __restrict__ cnt,
    int* __restrict__ tok, float* __restrict__ wgt, int4* __restrict__ tmap,
    const float* __restrict__ w13f, ushort* __restrict__ w13b)
{
  int t = blockIdx.x;
  int tid = threadIdx.x;
  const float4* xr  = (const float4*)(x + (size_t)t*HH);
  const float4* rs4 = (const float4*)rscale;
  float4 xa = xr[tid], xb = xr[tid+256];
  float4 sa = rs4[tid], sb = rs4[tid+256];
  double xd[8] = {xa.x,xa.y,xa.z,xa.w,xb.x,xb.y,xb.z,xb.w};
  double sd[8] = {sa.x,sa.y,sa.z,sa.w,sb.x,sb.y,sb.z,sb.w};
  double acc[9];
  double ss = 0.0;
  #pragma unroll
  for (int j=0;j<8;j++) ss += xd[j]*xd[j];
  acc[8] = ss;
  double xs[8];
  #pragma unroll
  for (int j=0;j<8;j++) xs[j] = xd[j]*sd[j];
  #pragma unroll
  for (int e=0;e<EE;e++){
    const float4* w4 = (const float4*)(rw + (size_t)e*HH);
    float4 wa = w4[tid], wb = w4[tid+256];
    double wd[8] = {wa.x,wa.y,wa.z,wa.w,wb.x,wb.y,wb.z,wb.w};
    double d = 0.0;
    #pragma unroll
    for (int j=0;j<8;j++) d += xs[j]*wd[j];
    acc[e] = d;
  }
  uint2 pa, pb;
  pa.x = (unsigned)f2bf(xa.x) | ((unsigned)f2bf(xa.y)<<16);
  pa.y = (unsigned)f2bf(xa.z) | ((unsigned)f2bf(xa.w)<<16);
  pb.x = (unsigned)f2bf(xb.x) | ((unsigned)f2bf(xb.y)<<16);
  pb.y = (unsigned)f2bf(xb.z) | ((unsigned)f2bf(xb.w)<<16);
  uint2* xo = (uint2*)(x16 + (size_t)t*HH);
  xo[tid] = pa; xo[tid+256] = pb;

  __shared__ double red[9*256];
  #pragma unroll
  for (int j=0;j<9;j++) red[j*256+tid] = acc[j];
  __syncthreads();
  for (int s=128;s>0;s>>=1){
    if (tid < s){
      #pragma unroll
      for (int j=0;j<9;j++) red[j*256+tid] += red[j*256+tid+s];
    }
    __syncthreads();
  }
  if (tid==0){
    double mean = red[8*256] / (double)HH;
    double rms  = 1.0 / sqrt(mean + 1e-6);
    double sc   = rms / sqrt((double)HH);
    double l[EE];
    #pragma unroll
    for (int e=0;e<EE;e++) l[e] = red[e*256]*sc;
    int i0 = 0;
    #pragma unroll
    for (int e=1;e<EE;e++) if (l[e] > l[i0]) i0 = e;
    int i1 = -1;
    #pragma unroll
    for (int e=0;e<EE;e++){ if (e==i0) continue; if (i1 < 0 || l[e] > l[i1]) i1 = e; }
    double p1 = exp(l[i1]-l[i0]);
    double s  = 1.0 + p1;
    float w0 = (float)((1.0/s) * (double)pes[i0]);
    float w1 = (float)((p1 /s) * (double)pes[i1]);
    int pos0 = atomicAdd(&cnt[i0],1);
    tok[i0*TT+pos0] = t; wgt[i0*TT+pos0] = w0;
    int pos1 = atomicAdd(&cnt[i1],1);
    tok[i1*TT+pos1] = t; wgt[i1*TT+pos1] = w1;
    tmap[t] = make_int4(i0,pos0,i1,pos1);
  }

  // ---- fused tail: convert w13 fp32 -> bf16 (4 grid-strided vec8 chunks) ----
  {
    size_t gid    = (size_t)t*256 + tid;
    size_t nchunk = (size_t)EE*2*DD*HH/8;   // 8,388,608
    size_t stride = (size_t)TT*256;         // 2,097,152
    for (size_t c = gid; c < nchunk; c += stride) CVT8(w13f, w13b, c);
  }
}

// ---- 8-phase machinery (round-2/4 schedule: reads before barrier, MFMA after) ----
// LDS tile: [256 rows][64 cols] bf16 per operand, double buffered. 16B chunk
// swizzle: slot c holds global chunk c ^ (row&7); reads apply same XOR.
#define STA(bb,h,t) do{ \
    GLOAD16(pA[2*(h)  ] + (size_t)(t)*64, &ldsA[bb][(h)*8192        + wid*512]); \
    GLOAD16(pA[2*(h)+1] + (size_t)(t)*64, &ldsA[bb][(h)*8192 + 4096 + wid*512]); }while(0)
#define STB(bb,h,t) do{ \
    GLOAD16(pB[2*(h)  ] + (size_t)(t)*64, &ldsB[bb][(h)*8192        + wid*512]); \
    GLOAD16(pB[2*(h)+1] + (size_t)(t)*64, &ldsB[bb][(h)*8192 + 4096 + wid*512]); }while(0)

#define RD_A(h) do{ _Pragma("unroll") \
  for (int mf=0;mf<4;mf++){ int row=(h)*128 + wm*64 + mf*16 + frow; \
    a[mf][0] = *(const bf16x8*)&As[row*64 + c0]; \
    a[mf][1] = *(const bf16x8*)&As[row*64 + c1]; } }while(0)
#define RD_B(h,bb_) do{ _Pragma("unroll") \
  for (int nf=0;nf<2;nf++){ int row=(h)*128 + wn*32 + nf*16 + frow; \
    bb_[nf][0] = *(const bf16x8*)&Bs[row*64 + c0]; \
    bb_[nf][1] = *(const bf16x8*)&Bs[row*64 + c1]; } }while(0)

#define MMQ(mo,no,bb_) do{ _Pragma("unroll") \
  for (int mf=0;mf<4;mf++){ _Pragma("unroll") \
    for (int nf=0;nf<2;nf++){ \
      acc[(mo)+mf][(no)+nf] = __builtin_amdgcn_mfma_f32_16x16x32_bf16(a[mf][0], bb_[nf][0], acc[(mo)+mf][(no)+nf],0,0,0); \
      acc[(mo)+mf][(no)+nf] = __builtin_amdgcn_mfma_f32_16x16x32_bf16(a[mf][1], bb_[nf][1], acc[(mo)+mf][(no)+nf],0,0,0); } } }while(0)

// Round-2/4 K-loop (measured best): 4 phases/K-tile; stages into t+1/t+2 slots;
// vmcnt(6) once per K-tile, never 0 mid-loop.
#define KLOOP for (int t=0;t<NT;t++){ \
    int cur=t&1, nxt=cur^1; \
    const ushort* As=&ldsA[cur][0]; const ushort* Bs=&ldsB[cur][0]; \
    RD_A(0); RD_B(0,b0); \
    if (t+1<NT) STA(nxt,1,t+1); \
    SBAR; BARR; WLG; SBAR; PRI(1); MMQ(0,0,b0); PRI(0); SBAR; BARR; SBAR; \
    RD_B(1,b1); \
    if (t+2<NT) STA(cur,0,t+2); \
    SBAR; BARR; WLG; SBAR; PRI(1); MMQ(0,2,b1); PRI(0); SBAR; BARR; SBAR; \
    RD_A(1); \
    if (t+2<NT) STB(cur,0,t+2); \
    SBAR; BARR; WLG; SBAR; PRI(1); MMQ(4,0,b0); PRI(0); SBAR; BARR; SBAR; \
    if (t+2<NT) STB(cur,1,t+2); \
    SBAR; BARR; SBAR; PRI(1); MMQ(4,2,b1); PRI(0); SBAR; WVM6; BARR; SBAR; \
  }

#define PROLOGUE \
  STA(0,0,0); STB(0,0,0); STB(0,1,0); STA(0,1,0); \
  STA(1,0,1); STB(1,0,1); STB(1,1,1); \
  SBAR; WVM6; BARR; SBAR;

// ---------------- GEMM1: 256 rows x 128 h-cols, gate/up interleaved in B ----------------
// + fused w2 fp32->bf16 conversion tail (runs on ALL blocks incl. early-exit)
__global__ __launch_bounds__(512,2) void ffn1_kernel(
    const ushort* __restrict__ x16, const ushort* __restrict__ w13,
    const int* __restrict__ cnt,
    const int* __restrict__ tok, ushort* __restrict__ hbuf,
    const float* __restrict__ w2f, ushort* __restrict__ w2b)
{
  // XCD-bijective swizzle (nwg=4096): XCD x owns expert x; n0 fastest within.
  int f = blockIdx.x + 16*(blockIdx.y + 32*blockIdx.z);
  int w = ((f&7)<<9) + (f>>3);
  int e  = w >> 9;
  int n0 = (w & 15) << 7;
  int m0 = ((w >> 4) & 31) << 8;
  int ce = cnt[e];

  __shared__ ushort ldsA[2][256*64];
  __shared__ ushort ldsB[2][256*64];

  int tid = threadIdx.x, wid = tid>>6, lane = tid&63;

  if (m0 < ce){
    // inline exclusive prefix (replaces scan_kernel)
    int oe = 0;
    for (int i=0;i<e;i++) oe += cnt[i];

    int wm = wid>>2, wn = wid&3;
    int frow = lane&15, klane = lane>>4;
    int c0 = ((klane  ) ^ (frow&7))<<3;
    int c1 = ((klane+4) ^ (frow&7))<<3;

    int r   = wid*8 + (lane>>3);             // staging row base (0..63)
    int csw = ((lane&7) ^ (lane>>3))<<3;     // inverse-swizzled source chunk

    const ushort* pA[4]; const ushort* pB[4];
    #pragma unroll
    for (int k=0;k<4;k++){
      int R  = k*64 + r;
      int ar = min(m0+R, ce-1);
      pA[k] = x16 + (size_t)tok[e*TT+ar]*HH + csw;
      int p = 2*k + (r>>5), mat = (r>>4)&1;
      pB[k] = w13 + (size_t)e*(2*DD)*HH + (size_t)(mat*DD + n0 + p*16 + (r&15))*HH + csw;
    }

    f32x4 acc[8][4];
    #pragma unroll
    for (int i=0;i<8;i++)
      #pragma unroll
      for (int j=0;j<4;j++) acc[i][j] = {0.f,0.f,0.f,0.f};
    bf16x8 a[4][2], b0[2][2], b1[2][2];

    PROLOGUE
    KLOOP

    #pragma unroll
    for (int mf=0;mf<8;mf++){
      int rb = ((mf<4)? wm*64 + mf*16 : 128 + wm*64 + (mf-4)*16) + klane*4;
      #pragma unroll
      for (int q=0;q<4;q++){
        int gm = m0 + rb + q;
        if (gm < ce){
          size_t hrow = (size_t)(oe+gm)*DD;
          #pragma unroll
          for (int pp=0;pp<2;pp++){
            float g = acc[mf][2*pp][q], u = acc[mf][2*pp+1][q];
            float t2 = 1.5957691216057308f*(g + 0.044715f*g*g*g);
            float sg = 1.f/(1.f+__expf(-t2));        // 0.5*(1+tanh(t)) = sigmoid(2t)
            hbuf[hrow + n0 + pp*64 + wn*16 + frow] = f2bf(g*u*sg);
          }
        }
      }
    }
  }

  // ---- fused tail: convert w2 fp32 -> bf16 (2 grid-strided vec8 chunks) ----
  {
    size_t gid    = (size_t)f*512 + tid;
    size_t nchunk = (size_t)EE*HH*DD/8;      // 4,194,304
    size_t stride = (size_t)4096*512;        // 2,097,152
    for (size_t c = gid; c < nchunk; c += stride) CVT8(w2f, w2b, c);
  }
}

// ---------------- GEMM2: 256 rows x 256 out-cols -> slot-major y (bf16, no atomics) ----------------
__global__ __launch_bounds__(512,2) void ffn2_kernel(
    const ushort* __restrict__ hbuf, const ushort* __restrict__ w2,
    const int* __restrict__ cnt,
    ushort* __restrict__ ybuf)
{
  // XCD-bijective swizzle (nwg=2048): XCD x owns expert x; n0 fastest.
  int f = blockIdx.x + 8*(blockIdx.y + 32*blockIdx.z);
  int w = ((f&7)<<8) + (f>>3);
  int e  = w >> 8;
  int n0 = (w & 7) << 8;
  int m0 = ((w >> 3) & 31) << 8;
  int ce = cnt[e];
  if (m0 >= ce) return;

  int oe = 0;
  for (int i=0;i<e;i++) oe += cnt[i];

  __shared__ ushort ldsA[2][256*64];
  __shared__ ushort ldsB[2][256*64];

  int tid = threadIdx.x, wid = tid>>6, lane = tid&63;
  int wm = wid>>2, wn = wid&3;
  int frow = lane&15, klane = lane>>4;
  int c0 = ((klane  ) ^ (frow&7))<<3;
  int c1 = ((klane+4) ^ (frow&7))<<3;

  int r   = wid*8 + (lane>>3);
  int csw = ((lane&7) ^ (lane>>3))<<3;

  const ushort* pA[4]; const ushort* pB[4];
  #pragma unroll
  for (int k=0;k<4;k++){
    int R  = k*64 + r;
    int ar = oe + min(m0+R, ce-1);
    pA[k] = hbuf + (size_t)ar*DD + csw;
    pB[k] = w2 + (size_t)e*HH*DD + (size_t)(n0 + R)*DD + csw;
  }

  f32x4 acc[8][4];
  #pragma unroll
  for (int i=0;i<8;i++)
    #pragma unroll
    for (int j=0;j<4;j++) acc[i][j] = {0.f,0.f,0.f,0.f};
  bf16x8 a[4][2], b0[2][2], b1[2][2];

  PROLOGUE
  KLOOP

  #pragma unroll
  for (int mf=0;mf<8;mf++){
    int rb = ((mf<4)? wm*64 + mf*16 : 128 + wm*64 + (mf-4)*16) + klane*4;
    #pragma unroll
    for (int q=0;q<4;q++){
      int gm = m0 + rb + q;
      if (gm < ce){
        size_t yrow = (size_t)(oe+gm)*HH;
        #pragma unroll
        for (int nf=0;nf<4;nf++){
          int col = (nf>>1)*128 + wn*32 + (nf&1)*16 + frow;
          ybuf[yrow + n0 + col] = f2bf(acc[mf][nf][q]);   // plain store, no RMW
        }
      }
    }
  }
}

// ---------------- combine: out[t] = w0*y[slot0] + w1*y[slot1] (coalesced gather) ----------------
__global__ __launch_bounds__(256) void combine_kernel(
    const ushort* __restrict__ ybuf, const int4* __restrict__ tmap,
    const float* __restrict__ wgt, const int* __restrict__ cnt,
    float* __restrict__ out)
{
  int t = blockIdx.x, tid = threadIdx.x;
  int4 m = tmap[t];
  // inline exclusive prefix (replaces scan_kernel)
  int pre[EE]; int a_ = 0;
  #pragma unroll
  for (int i=0;i<EE;i++){ pre[i] = a_; a_ += cnt[i]; }
  float w0 = wgt[m.x*TT + m.y];
  float w1 = wgt[m.z*TT + m.w];
  const ushort* y0 = ybuf + (size_t)(pre[m.x] + m.y)*HH + tid*8;
  const ushort* y1 = ybuf + (size_t)(pre[m.z] + m.w)*HH + tid*8;
  uint4 v0 = *(const uint4*)y0;
  uint4 v1 = *(const uint4*)y1;
  float* o = out + (size_t)t*HH + tid*8;
  const unsigned* a0 = (const unsigned*)&v0;
  const unsigned* a1 = (const unsigned*)&v1;
  float r[8];
  #pragma unroll
  for (int j=0;j<4;j++){
    float lo0 = __uint_as_float(a0[j]<<16), hi0 = __uint_as_float(a0[j]&0xffff0000u);
    float lo1 = __uint_as_float(a1[j]<<16), hi1 = __uint_as_float(a1[j]&0xffff0000u);
    r[2*j]   = w0*lo0 + w1*lo1;
    r[2*j+1] = w0*hi0 + w1*hi1;
  }
  f32x4v r0 = {r[0],r[1],r[2],r[3]};
  f32x4v r1 = {r[4],r[5],r[6],r[7]};
  __builtin_nontemporal_store(r0, (f32x4v*)o);      // out never re-read
  __builtin_nontemporal_store(r1, (f32x4v*)(o+4));
}

extern "C" void kernel_launch(void* const* d_in, const int* in_sizes, int n_in,
                              void* d_out, int out_size, void* d_ws, size_t ws_size,
                              hipStream_t stream)
{
  const float* x    = (const float*)d_in[0];
  const float* rsc  = (const float*)d_in[1];
  const float* pes  = (const float*)d_in[2];
  const float* rw   = (const float*)d_in[3];
  const float* w13f = (const float*)d_in[4];
  const float* w2f  = (const float*)d_in[5];
  float* out = (float*)d_out;

  char* ws = (char*)d_ws;
  size_t o_x16 = 0;
  size_t o_w13 = o_x16 + (size_t)TT*HH*2;          // x16:  32 MiB
  size_t o_w2  = o_w13 + (size_t)EE*2*DD*HH*2;     // w13b: 128 MiB (ybuf aliases after ffn1)
  size_t o_h   = o_w2  + (size_t)EE*HH*DD*2;       // w2b:  64 MiB
  size_t o_cnt = o_h   + (size_t)2*TT*DD*2;        // h:    64 MiB
  size_t o_tok = o_cnt + 128;
  size_t o_wgt = o_tok + (size_t)EE*TT*4;
  size_t o_map = o_wgt + (size_t)EE*TT*4;
  size_t need  = o_map + (size_t)TT*16;

  if (ws_size < need){ hipMemsetAsync(d_out, 0, (size_t)TT*HH*4, stream); return; }

  ushort* x16 = (ushort*)(ws + o_x16);
  ushort* w13b= (ushort*)(ws + o_w13);
  ushort* w2b = (ushort*)(ws + o_w2);
  ushort* hbuf= (ushort*)(ws + o_h);
  ushort* ybuf= (ushort*)(ws + o_w13);             // alias: w13b dead after ffn1
  int*   cnt  = (int*)(ws + o_cnt);
  int*   tok  = (int*)(ws + o_tok);
  float* wgt  = (float*)(ws + o_wgt);
  int4*  tmap = (int4*)(ws + o_map);

  hipMemsetAsync(cnt, 0, EE*sizeof(int), stream);
  router_kernel<<<TT,256,0,stream>>>(x, rsc, pes, rw, x16, cnt, tok, wgt, tmap, w13f, w13b);
  dim3 g1(DD/128, TT/256, EE);   // 16 x 32 x 8 = 4096
  ffn1_kernel<<<g1,512,0,stream>>>(x16, w13b, cnt, tok, hbuf, w2f, w2b);
  dim3 g2(HH/256, TT/256, EE);   // 8 x 32 x 8 = 2048
  ffn2_kernel<<<g2,512,0,stream>>>(hbuf, w2b, cnt, ybuf);
  combine_kernel<<<TT,256,0,stream>>>(ybuf, tmap, wgt, cnt, out);
}